// Round 20
// baseline (821.864 us; speedup 1.0000x reference)
//
#include <hip/hip_runtime.h>
#include <cstdint>
#include <cstddef>

// ---------------------------------------------------------------------------
// EGT layer.  N nodes (DIM=96, H=32, HD=3), E edges.
// CSR slotinfo[slot]={eidx,src,dst,0}; qkv bf16-only; weights prepped bf16.
// edge_tile: 64 CSR slots/block, bf16 sEV, direct eout write, 25.6KB LDS
// -> 6 blocks/CU.  mlp: fused node MLP, bf16 hp, 52.2KB LDS -> 3 blocks/CU.
// gather: 4-deep load pipeline.
// ---------------------------------------------------------------------------

typedef short  s16x8 __attribute__((ext_vector_type(8)));
typedef short  s16x4 __attribute__((ext_vector_type(4)));
typedef float  f32x4 __attribute__((ext_vector_type(4)));

__device__ __forceinline__ unsigned short f2b(float x) {
    union { float f; unsigned u; } v; v.f = x;
    unsigned r = v.u + 0x7FFF + ((v.u >> 16) & 1);   // RNE
    return (unsigned short)(r >> 16);
}
__device__ __forceinline__ float b2f(unsigned short u) {
    union { unsigned u; float f; } v; v.u = ((unsigned)u) << 16; return v.f;
}

// ---------------- MFMA node GEMM (qkv MULTI) ----------------
template<int MULTI, int LNA, int A16, int RELU, int RES>
__global__ __launch_bounds__(256) void mgemm_kernel(
    const void* __restrict__ Av, int lda,
    const float* __restrict__ B0, const float* __restrict__ B1,
    const float* __restrict__ B2, int ldb,
    const float* __restrict__ bias0, const float* __restrict__ bias1,
    const float* __restrict__ bias2,
    const float* __restrict__ lng, const float* __restrict__ lnbv,
    const float* __restrict__ resid, const float* __restrict__ wptr,
    float* __restrict__ C, int ldc, unsigned short* __restrict__ C16,
    int M, int K)
{
    __shared__ unsigned short sAL[64 * 200];
    __shared__ unsigned short sB[96 * 40];

    const int tid = threadIdx.x;
    const int m0 = blockIdx.x * 64;
    const int y  = blockIdx.y;
    const float* B = MULTI ? (y == 0 ? B0 : (y == 1 ? B1 : B2)) : B0;
    const int nbB = MULTI ? 0 : y * 96;
    const int nbC = y * 96;
    const int w = tid >> 6, l = tid & 63, fr = l & 15, kg = l >> 4;
    const int KP = K + 8;

    if (LNA) {
        const float* Af = (const float*)Av;
        const int row = 16 * w + fr;
        const int grow = m0 + row;
        float x[24];
        if (grow < M) {
            #pragma unroll
            for (int t = 0; t < 6; t++)
                *(float4*)&x[t * 4] = *(const float4*)(Af + (size_t)grow * lda + 24 * kg + t * 4);
        } else {
            #pragma unroll
            for (int t = 0; t < 24; t++) x[t] = 0.f;
        }
        float s = 0.f;
        #pragma unroll
        for (int t = 0; t < 24; t++) s += x[t];
        s += __shfl_xor(s, 16, 64); s += __shfl_xor(s, 32, 64);
        float mu = s * (1.f / 96.f);
        float v2 = 0.f;
        #pragma unroll
        for (int t = 0; t < 24; t++) { float d = x[t] - mu; v2 += d * d; }
        v2 += __shfl_xor(v2, 16, 64); v2 += __shfl_xor(v2, 32, 64);
        float rs = rsqrtf(v2 * (1.f / 96.f) + 1e-5f);
        #pragma unroll
        for (int t3 = 0; t3 < 3; t3++) {
            s16x8 yv;
            #pragma unroll
            for (int u = 0; u < 8; u++) {
                int cidx = 24 * kg + t3 * 8 + u;
                yv[u] = (short)f2b((x[t3 * 8 + u] - mu) * rs * lng[cidx] + lnbv[cidx]);
            }
            *(s16x8*)&sAL[row * KP + 24 * kg + t3 * 8] = yv;
        }
    } else {
        const int nseg = K >> 3;
        for (int idx = tid; idx < 64 * nseg; idx += 256) {
            int row = idx / nseg, k8 = (idx - row * nseg) * 8;
            int grow = m0 + row;
            s16x8 a8 = (s16x8){0, 0, 0, 0, 0, 0, 0, 0};
            if (grow < M) {
                if (A16) {
                    a8 = *(const s16x8*)((const unsigned short*)Av + (size_t)grow * lda + k8);
                } else {
                    const float* Af = (const float*)Av;
                    float4 v0 = *(const float4*)(Af + (size_t)grow * lda + k8);
                    float4 v1 = *(const float4*)(Af + (size_t)grow * lda + k8 + 4);
                    a8[0] = (short)f2b(v0.x); a8[1] = (short)f2b(v0.y);
                    a8[2] = (short)f2b(v0.z); a8[3] = (short)f2b(v0.w);
                    a8[4] = (short)f2b(v1.x); a8[5] = (short)f2b(v1.y);
                    a8[6] = (short)f2b(v1.z); a8[7] = (short)f2b(v1.w);
                }
            }
            *(s16x8*)&sAL[row * KP + k8] = a8;
        }
    }

    f32x4 acc[6];
    #pragma unroll
    for (int i = 0; i < 6; i++) acc[i] = (f32x4){0.f, 0.f, 0.f, 0.f};

    for (int kc = 0; kc < K; kc += 32) {
        #pragma unroll
        for (int r = 0; r < 3; r++) {
            int idx = tid + 256 * r;
            int k = idx / 24, n4 = (idx - k * 24) * 4;
            float4 v = *(const float4*)(B + (size_t)(kc + k) * ldb + nbB + n4);
            sB[(n4 + 0) * 40 + k] = f2b(v.x);
            sB[(n4 + 1) * 40 + k] = f2b(v.y);
            sB[(n4 + 2) * 40 + k] = f2b(v.z);
            sB[(n4 + 3) * 40 + k] = f2b(v.w);
        }
        __syncthreads();
        {
            s16x8 a = *(s16x8*)&sAL[(16 * w + fr) * KP + kc + kg * 8];
            #pragma unroll
            for (int nt = 0; nt < 6; nt++) {
                s16x8 b = *(s16x8*)&sB[(16 * nt + fr) * 40 + kg * 8];
                acc[nt] = __builtin_amdgcn_mfma_f32_16x16x32_bf16(a, b, acc[nt], 0, 0, 0);
            }
        }
        __syncthreads();
    }

    const float* biasp = MULTI ? (y == 0 ? bias0 : (y == 1 ? bias1 : bias2)) : bias0;
    const int bbase = MULTI ? 0 : nbB;

    #pragma unroll
    for (int nt = 0; nt < 6; nt++) {
        int cl = nt * 16 + fr;
        float bv = biasp[bbase + cl];
        int gcol = nbC + cl;
        #pragma unroll
        for (int r = 0; r < 4; r++) {
            int row = m0 + 16 * w + 4 * kg + r;
            if (row >= M) continue;
            float v = acc[nt][r] + bv;
            if (RELU) v = fmaxf(v, 0.f);
            if (MULTI) {
                C16[(size_t)row * 288 + gcol] = f2b(v);
            } else {
                C[(size_t)row * ldc + gcol] = v;
            }
        }
    }
}

// ---------------- prep: all static weights -> bf16 [N][K] (once) ----------
__global__ __launch_bounds__(256) void prep_kernel(
    const float* __restrict__ Wb, const float* __restrict__ We,
    const float* __restrict__ Wf0, const float* __restrict__ Wf1,
    const float* __restrict__ Wvv, const float* __restrict__ Wm0,
    const float* __restrict__ Wm1,
    unsigned short* __restrict__ WbWe16, unsigned short* __restrict__ Wf0T16,
    unsigned short* __restrict__ Wf1T16, unsigned short* __restrict__ WvvT16,
    unsigned short* __restrict__ Wm0T16, unsigned short* __restrict__ Wm1T16)
{
    const int t = threadIdx.x;
    for (int i = t; i < 2048; i += 256) {
        int n = i >> 5, k = i & 31;
        float v = (n < 32) ? Wb[k * 32 + n] : We[k * 32 + (n - 32)];
        WbWe16[i] = f2b(v);
    }
    for (int i = t; i < 2048; i += 256) {
        int n = i >> 5, k = i & 31;
        Wf0T16[i] = f2b(Wf0[k * 64 + n]);
    }
    for (int i = t; i < 2048; i += 256) {
        int n = i >> 6, k = i & 63;
        Wf1T16[i] = f2b(Wf1[k * 32 + n]);
    }
    for (int i = t; i < 12288; i += 256) {
        int n = i >> 7, k = i & 127;
        WvvT16[i] = f2b(Wvv[k * 96 + n]);
    }
    for (int i = t; i < 18432; i += 256) {
        int n = i / 96, k = i - n * 96;
        Wm0T16[i] = f2b(Wm0[k * 192 + n]);
    }
    for (int i = t; i < 18432; i += 256) {
        int n = i / 192, k = i - n * 192;
        Wm1T16[i] = f2b(Wm1[k * 96 + n]);
    }
}

// ---------------- CSR bucketing ----------------
__global__ __launch_bounds__(256) void count_kernel(
    const int* __restrict__ dst, int* __restrict__ cnt,
    int* __restrict__ rank, int E)
{
    int i = blockIdx.x * 256 + threadIdx.x;
    if (i < E) rank[i] = atomicAdd(&cnt[dst[i]], 1);
}

__global__ __launch_bounds__(1024) void scan_kernel(
    const int* __restrict__ cnt, int* __restrict__ off, int N)
{
    __shared__ int s[1024];
    const int tid = threadIdx.x;
    const int chunk = (N + 1023) >> 10;
    const int lo = tid * chunk;
    const int hi = min(lo + chunk, N);
    int sum = 0;
    for (int i = lo; i < hi; i++) sum += cnt[i];
    s[tid] = sum;
    __syncthreads();
    for (int d = 1; d < 1024; d <<= 1) {
        int v = (tid >= d) ? s[tid - d] : 0;
        __syncthreads();
        s[tid] += v;
        __syncthreads();
    }
    int base = (tid == 0) ? 0 : s[tid - 1];
    for (int i = lo; i < hi; i++) {
        off[i] = base;
        base += cnt[i];
    }
}

__global__ __launch_bounds__(256) void scatter_kernel(
    const int* __restrict__ dst, const int* __restrict__ src,
    const int* __restrict__ off, const int* __restrict__ rank,
    int4* __restrict__ slotinfo, int E)
{
    int i = blockIdx.x * 256 + threadIdx.x;
    if (i < E) {
        int d = dst[i];
        int p = off[d] + rank[i];
        slotinfo[p] = make_int4(i, src[i], d, 0);
    }
}

// ---------------- edge tile kernel: 64 CSR slots per block ------------------
__global__ __launch_bounds__(256, 6) void edge_tile_kernel(
    const float* __restrict__ edge, const unsigned short* __restrict__ qkv16,
    const int4* __restrict__ slotinfo,
    const unsigned short* __restrict__ WbWe16,
    const unsigned short* __restrict__ Wf0T16,
    const unsigned short* __restrict__ Wf1T16,
    const float* __restrict__ be, const float* __restrict__ bb,
    const float* __restrict__ bf0, const float* __restrict__ bf1,
    const float* __restrict__ ge0, const float* __restrict__ be0,
    const float* __restrict__ ge1, const float* __restrict__ be1,
    unsigned short* __restrict__ exve16, float* __restrict__ eout, int E)
{
    __shared__ unsigned short sEV[64 * 40];   // ev -> er (bf16)
    __shared__ unsigned short sQK[64 * 44];   // qk bf16 (pad 44)
    __shared__ unsigned short sA [64 * 40];   // ew/en bf16
    __shared__ unsigned short sX [64 * 76];   // ex|ve then F (pad 76)
    // total 25,600 B -> 6 blocks/CU

    const int tid = threadIdx.x;
    const long long e0 = (long long)blockIdx.x * 64;
    const int w  = tid >> 6;
    const int l  = tid & 63;
    const int fr = l & 15;
    const int kg = l >> 4;

    // ---- S1a: fused score from bf16 qkv16 (CSR order, q[dst] hot) ----
    {
        const int row = tid >> 2;
        const int j   = tid & 3;
        long long s = e0 + row;
        float qv[24], kv[24];
        if (s < E) {
            int4 si = slotinfo[s];
            const unsigned short* qp = qkv16 + (size_t)si.z * 288 + 24 * j;
            const unsigned short* kp = qkv16 + (size_t)si.y * 288 + 96 + 24 * j;
            #pragma unroll
            for (int t = 0; t < 3; t++) {
                s16x8 qa = *(const s16x8*)(qp + 8 * t);
                s16x8 ka = *(const s16x8*)(kp + 8 * t);
                #pragma unroll
                for (int u = 0; u < 8; u++) {
                    qv[8 * t + u] = b2f((unsigned short)qa[u]);
                    kv[8 * t + u] = b2f((unsigned short)ka[u]);
                }
            }
        } else {
            #pragma unroll
            for (int t = 0; t < 24; t++) { qv[t] = 0.f; kv[t] = 0.f; }
        }
        s16x8 qkb;
        #pragma unroll
        for (int t = 0; t < 8; t++) {
            float d = kv[3*t]*qv[3*t] + kv[3*t+1]*qv[3*t+1] + kv[3*t+2]*qv[3*t+2];
            qkb[t] = (short)f2b(0.5f * d);
        }
        *(s16x8*)&sQK[row * 44 + 8 * j] = qkb;
    }
    // ---- S1b: stage ev rows (bf16, via slotinfo.x) ----
    #pragma unroll
    for (int rr = 0; rr < 2; rr++) {
        int idx = tid + 256 * rr;
        int row = idx >> 3, c4 = (idx & 7) * 4;
        long long s = e0 + row;
        float4 v = make_float4(0.f, 0.f, 0.f, 0.f);
        if (s < E) {
            int ge = slotinfo[s].x;
            v = *(const float4*)(edge + (size_t)ge * 32 + c4);
        }
        s16x4 vb; vb[0] = (short)f2b(v.x); vb[1] = (short)f2b(v.y);
        vb[2] = (short)f2b(v.z); vb[3] = (short)f2b(v.w);
        *(s16x4*)&sEV[row * 40 + c4] = vb;
    }
    __syncthreads();

    // ---- S2: LN1 -> ew rows (bf16) in sA ----
    {
        const int row = 16 * w + (tid & 15);
        const int q = (tid & 63) >> 4;
        s16x8 xa = *(s16x8*)&sEV[row * 40 + 8 * q];
        float x[8];
        #pragma unroll
        for (int u = 0; u < 8; u++) x[u] = b2f((unsigned short)xa[u]);
        float s = x[0] + x[1] + x[2] + x[3] + x[4] + x[5] + x[6] + x[7];
        s += __shfl_xor(s, 16, 64); s += __shfl_xor(s, 32, 64);
        float mu = s * (1.f / 32.f);
        float v2 = 0.f;
        #pragma unroll
        for (int i = 0; i < 8; i++) { float d = x[i] - mu; v2 += d * d; }
        v2 += __shfl_xor(v2, 16, 64); v2 += __shfl_xor(v2, 32, 64);
        float rs = rsqrtf(v2 * (1.f / 32.f) + 1e-5f);
        float4 g1 = *(const float4*)(ge0 + 8 * q), g2 = *(const float4*)(ge0 + 8 * q + 4);
        float4 b1 = *(const float4*)(be0 + 8 * q), b2 = *(const float4*)(be0 + 8 * q + 4);
        float gg[8] = {g1.x, g1.y, g1.z, g1.w, g2.x, g2.y, g2.z, g2.w};
        float bs[8] = {b1.x, b1.y, b1.z, b1.w, b2.x, b2.y, b2.z, b2.w};
        s16x8 y;
        #pragma unroll
        for (int i = 0; i < 8; i++)
            y[i] = (short)f2b((x[i] - mu) * rs * gg[i] + bs[i]);
        *(s16x8*)&sA[row * 40 + 8 * q] = y;
    }
    __builtin_amdgcn_wave_barrier();

    // ---- S3: GEMM1 (MFMA)  [64][64 = sc|veh] = ew @ [Wb|We] ----
    f32x4 acc[4];
    {
        s16x8 a = *(s16x8*)&sA[(16 * w + fr) * 40 + kg * 8];
        #pragma unroll
        for (int nt = 0; nt < 4; nt++) {
            s16x8 b = *(const s16x8*)(WbWe16 + (16 * nt + fr) * 32 + kg * 8);
            f32x4 z = {0.f, 0.f, 0.f, 0.f};
            acc[nt] = __builtin_amdgcn_mfma_f32_16x16x32_bf16(a, b, z, 0, 0, 0);
        }
    }

    // ---- S4: epilogue1 (ex|ve -> sX; er -> sEV bf16), wave-local rows ----
    #pragma unroll
    for (int nt = 0; nt < 2; nt++) {
        int col = nt * 16 + fr;
        float bbv = bb[col];
        #pragma unroll
        for (int r = 0; r < 4; r++) {
            int row = 16 * w + 4 * kg + r;
            float sc = acc[nt][r] + b2f(sQK[row * 44 + col]) + bbv;
            sX[row * 76 + col] = f2b(__expf(sc));
            float er = sc + b2f(sEV[row * 40 + col]);
            sEV[row * 40 + col] = f2b(er);
        }
    }
    #pragma unroll
    for (int nt = 2; nt < 4; nt++) {
        int col = (nt - 2) * 16 + fr;
        float bev = be[col];
        #pragma unroll
        for (int r = 0; r < 4; r++) {
            int row = 16 * w + 4 * kg + r;
            sX[row * 76 + 32 + col] = f2b(acc[nt][r] + bev);
        }
    }
    __syncthreads();

    // ---- S5a: copy sX -> exve16 (contiguous at slot); S5b: LN2 -> sA ----
    #pragma unroll
    for (int rr = 0; rr < 2; rr++) {
        int idx = tid + 256 * rr;
        int row = idx >> 3, c8 = (idx & 7) * 8;
        long long s = e0 + row;
        if (s < E)
            *(s16x8*)(exve16 + (size_t)s * 64 + c8) = *(s16x8*)&sX[row * 76 + c8];
    }
    {
        const int row = 16 * w + (tid & 15);
        const int q = (tid & 63) >> 4;
        s16x8 xa = *(s16x8*)&sEV[row * 40 + 8 * q];
        float x[8];
        #pragma unroll
        for (int u = 0; u < 8; u++) x[u] = b2f((unsigned short)xa[u]);
        float s = x[0] + x[1] + x[2] + x[3] + x[4] + x[5] + x[6] + x[7];
        s += __shfl_xor(s, 16, 64); s += __shfl_xor(s, 32, 64);
        float mu = s * (1.f / 32.f);
        float v2 = 0.f;
        #pragma unroll
        for (int i = 0; i < 8; i++) { float d = x[i] - mu; v2 += d * d; }
        v2 += __shfl_xor(v2, 16, 64); v2 += __shfl_xor(v2, 32, 64);
        float rs = rsqrtf(v2 * (1.f / 32.f) + 1e-5f);
        float4 g1 = *(const float4*)(ge1 + 8 * q), g2 = *(const float4*)(ge1 + 8 * q + 4);
        float4 b1 = *(const float4*)(be1 + 8 * q), b2 = *(const float4*)(be1 + 8 * q + 4);
        float gg[8] = {g1.x, g1.y, g1.z, g1.w, g2.x, g2.y, g2.z, g2.w};
        float bs[8] = {b1.x, b1.y, b1.z, b1.w, b2.x, b2.y, b2.z, b2.w};
        s16x8 y;
        #pragma unroll
        for (int i = 0; i < 8; i++)
            y[i] = (short)f2b((x[i] - mu) * rs * gg[i] + bs[i]);
        *(s16x8*)&sA[row * 40 + 8 * q] = y;
    }
    __syncthreads();   // sX must be fully copied out before S6 overwrites it

    // ---- S6: GEMM2 (MFMA)  F[64][64] = relu(en @ Wf0 + bf0) -> sX ----
    {
        s16x8 a = *(s16x8*)&sA[(16 * w + fr) * 40 + kg * 8];
        #pragma unroll
        for (int nt = 0; nt < 4; nt++) {
            s16x8 b = *(const s16x8*)(Wf0T16 + (16 * nt + fr) * 32 + kg * 8);
            f32x4 z = {0.f, 0.f, 0.f, 0.f};
            f32x4 a2 = __builtin_amdgcn_mfma_f32_16x16x32_bf16(a, b, z, 0, 0, 0);
            int col = nt * 16 + fr;
            float b0v = bf0[col];
            #pragma unroll
            for (int r = 0; r < 4; r++) {
                int row = 16 * w + 4 * kg + r;
                sX[row * 76 + col] = f2b(fmaxf(a2[r] + b0v, 0.f));
            }
        }
    }
    __builtin_amdgcn_wave_barrier();

    // ---- S7: GEMM3 (MFMA)  out = F @ Wf1 + er + bf1 -> eout DIRECT ----
    {
        s16x8 a0 = *(s16x8*)&sX[(16 * w + fr) * 76 + kg * 8];
        s16x8 a1 = *(s16x8*)&sX[(16 * w + fr) * 76 + 32 + kg * 8];
        #pragma unroll
        for (int nt = 0; nt < 2; nt++) {
            s16x8 b0 = *(const s16x8*)(Wf1T16 + (16 * nt + fr) * 64 + kg * 8);
            s16x8 b1 = *(const s16x8*)(Wf1T16 + (16 * nt + fr) * 64 + 32 + kg * 8);
            f32x4 z = {0.f, 0.f, 0.f, 0.f};
            f32x4 t = __builtin_amdgcn_mfma_f32_16x16x32_bf16(a0, b0, z, 0, 0, 0);
            t = __builtin_amdgcn_mfma_f32_16x16x32_bf16(a1, b1, t, 0, 0, 0);
            int col = nt * 16 + fr;
            float bf1v = bf1[col];
            #pragma unroll
            for (int r = 0; r < 4; r++) {
                int row = 16 * w + 4 * kg + r;
                long long s = e0 + row;
                if (s < E) {
                    int ge = slotinfo[s].x;
                    eout[(size_t)ge * 32 + col] =
                        t[r] + b2f(sEV[row * 40 + col]) + bf1v;
                }
            }
        }
    }
}

// ---------------- gather: wave/node, 4 edges in flight per half ------------
__global__ __launch_bounds__(256) void gather_kernel(
    const unsigned short* __restrict__ exve16, const unsigned short* __restrict__ qkv16,
    const int4* __restrict__ slotinfo, const int* __restrict__ off,
    const int* __restrict__ cnt, unsigned short* __restrict__ agg16, int N)
{
    __shared__ unsigned short sV16[4][2][4][96];
    __shared__ unsigned short sE16[4][2][4][64];
    const int wave = threadIdx.x >> 6;
    const int lane = threadIdx.x & 63;
    const int head = lane & 31;
    const int half = lane >> 5;
    int n = blockIdx.x * 4 + wave;
    if (n >= N) return;
    const int o = off[n], d = cnt[n];
    float a0 = 0.f, a1 = 0.f, a2 = 0.f, a3 = 0.f, den = 0.f;
    for (int i = half; i < d; i += 8) {
        #pragma unroll
        for (int b = 0; b < 4; b++) {
            int ii = i + 2 * b;
            if (ii < d) {
                int sn = slotinfo[o + ii].y;
                const unsigned short* vr = qkv16 + (size_t)sn * 288 + 192;
                const unsigned short* er = exve16 + (size_t)(o + ii) * 64;
                if (head < 12)
                    *(s16x8*)&sV16[wave][half][b][head * 8] = *(const s16x8*)(vr + head * 8);
                else if (head >= 24)
                    *(s16x8*)&sE16[wave][half][b][(head - 24) * 8] = *(const s16x8*)(er + (head - 24) * 8);
            }
        }
        __builtin_amdgcn_wave_barrier();
        #pragma unroll
        for (int b = 0; b < 4; b++) {
            int ii = i + 2 * b;
            if (ii < d) {
                float ex = b2f(sE16[wave][half][b][head]);
                float vv = b2f(sE16[wave][half][b][32 + head]);
                a0 += ex * b2f(sV16[wave][half][b][head * 3]);
                a1 += ex * b2f(sV16[wave][half][b][head * 3 + 1]);
                a2 += ex * b2f(sV16[wave][half][b][head * 3 + 2]);
                a3 += ex * vv;
                den += ex;
            }
        }
        __builtin_amdgcn_wave_barrier();
    }
    a0 += __shfl_xor(a0, 32, 64);
    a1 += __shfl_xor(a1, 32, 64);
    a2 += __shfl_xor(a2, 32, 64);
    a3 += __shfl_xor(a3, 32, 64);
    den += __shfl_xor(den, 32, 64);
    if (half == 0) {
        float sc = (d > 0) ? 1.f / den : 0.f;
        s16x4 ov;
        ov[0] = (short)f2b(a0 * sc);
        ov[1] = (short)f2b(a1 * sc);
        ov[2] = (short)f2b(a2 * sc);
        ov[3] = (short)f2b(a3 * sc);
        *(s16x4*)(agg16 + (size_t)n * 128 + head * 4) = ov;
    }
}

// ---------------- fused node MLP: Wvv+res -> LN -> Wm0+relu -> Wm1+res -----
__global__ __launch_bounds__(256, 3) void mlp_kernel(
    const unsigned short* __restrict__ agg16, const float* __restrict__ feat,
    const unsigned short* __restrict__ WvvT16,
    const unsigned short* __restrict__ Wm0T16,
    const unsigned short* __restrict__ Wm1T16,
    const float* __restrict__ bvv, const float* __restrict__ bm0,
    const float* __restrict__ bm1,
    const float* __restrict__ g_m, const float* __restrict__ b_m,
    const float* __restrict__ wsc,
    float* __restrict__ hout, int M)
{
    __shared__ unsigned short sU[64 * 200];   // agg tile (stride 136) then F (stride 200)
    __shared__ unsigned short sHP[64 * 104];  // h_pre rows (bf16)
    __shared__ unsigned short sA[64 * 104];   // LN(h_pre) bf16
    // total 52,224 B -> 3 blocks/CU

    const int tid = threadIdx.x;
    const int m0 = blockIdx.x * 64;
    const int w = tid >> 6, l = tid & 63, fr = l & 15, kg = l >> 4;

    #pragma unroll
    for (int r = 0; r < 4; r++) {
        int s1 = tid + 256 * r;
        int row = s1 >> 4, k8 = (s1 & 15) * 8;
        int grow = m0 + row;
        s16x8 a8 = (s16x8){0, 0, 0, 0, 0, 0, 0, 0};
        if (grow < M) a8 = *(const s16x8*)(agg16 + (size_t)grow * 128 + k8);
        *(s16x8*)&sU[row * 136 + k8] = a8;
    }
    __syncthreads();
    const float w0 = 1.f + wsc[0];

    // ---- GEMM1: hp[64][96] = agg @ WvvT (K=128) + bvv + w0*feat ----
    {
        f32x4 acc[6];
        #pragma unroll
        for (int i = 0; i < 6; i++) acc[i] = (f32x4){0.f, 0.f, 0.f, 0.f};
        #pragma unroll
        for (int kc = 0; kc < 128; kc += 32) {
            s16x8 a = *(s16x8*)&sU[(16 * w + fr) * 136 + kc + kg * 8];
            #pragma unroll
            for (int nt = 0; nt < 6; nt++) {
                s16x8 b = *(const s16x8*)(WvvT16 + (16 * nt + fr) * 128 + kc + kg * 8);
                acc[nt] = __builtin_amdgcn_mfma_f32_16x16x32_bf16(a, b, acc[nt], 0, 0, 0);
            }
        }
        #pragma unroll
        for (int nt = 0; nt < 6; nt++) {
            int col = nt * 16 + fr;
            float bv = bvv[col];
            #pragma unroll
            for (int r = 0; r < 4; r++) {
                int row = 16 * w + 4 * kg + r;
                int grow = m0 + row;
                float fv = (grow < M) ? feat[(size_t)grow * 96 + col] : 0.f;
                sHP[row * 104 + col] = f2b(acc[nt][r] + bv + w0 * fv);
            }
        }
    }
    __syncthreads();

    // ---- LN over hp rows -> sA bf16 ----
    {
        const int row = 16 * w + (tid & 15);
        const int q = (tid & 63) >> 4;
        float x[24];
        #pragma unroll
        for (int t = 0; t < 3; t++) {
            s16x8 xa = *(s16x8*)&sHP[row * 104 + 24 * q + 8 * t];
            #pragma unroll
            for (int u = 0; u < 8; u++) x[8 * t + u] = b2f((unsigned short)xa[u]);
        }
        float s = 0.f;
        #pragma unroll
        for (int t = 0; t < 24; t++) s += x[t];
        s += __shfl_xor(s, 16, 64); s += __shfl_xor(s, 32, 64);
        float mu = s * (1.f / 96.f);
        float v2 = 0.f;
        #pragma unroll
        for (int t = 0; t < 24; t++) { float d = x[t] - mu; v2 += d * d; }
        v2 += __shfl_xor(v2, 16, 64); v2 += __shfl_xor(v2, 32, 64);
        float rs = rsqrtf(v2 * (1.f / 96.f) + 1e-5f);
        #pragma unroll
        for (int t3 = 0; t3 < 3; t3++) {
            s16x8 yv;
            #pragma unroll
            for (int u = 0; u < 8; u++) {
                int cidx = 24 * q + t3 * 8 + u;
                yv[u] = (short)f2b((x[t3 * 8 + u] - mu) * rs * g_m[cidx] + b_m[cidx]);
            }
            *(s16x8*)&sA[row * 104 + 24 * q + t3 * 8] = yv;
        }
    }
    __builtin_amdgcn_wave_barrier();

    // ---- GEMM2: F[64][192] = relu(LN @ Wm0T + bm0) (K=96) -> sU stride 200 --
    {
        f32x4 acc2[12];
        #pragma unroll
        for (int i = 0; i < 12; i++) acc2[i] = (f32x4){0.f, 0.f, 0.f, 0.f};
        #pragma unroll
        for (int kc = 0; kc < 96; kc += 32) {
            s16x8 a = *(s16x8*)&sA[(16 * w + fr) * 104 + kc + kg * 8];
            #pragma unroll
            for (int nt = 0; nt < 12; nt++) {
                s16x8 b = *(const s16x8*)(Wm0T16 + (16 * nt + fr) * 96 + kc + kg * 8);
                acc2[nt] = __builtin_amdgcn_mfma_f32_16x16x32_bf16(a, b, acc2[nt], 0, 0, 0);
            }
        }
        #pragma unroll
        for (int nt = 0; nt < 12; nt++) {
            int col = nt * 16 + fr;
            float b0 = bm0[col];
            #pragma unroll
            for (int r = 0; r < 4; r++) {
                int row = 16 * w + 4 * kg + r;
                sU[row * 200 + col] = f2b(fmaxf(acc2[nt][r] + b0, 0.f));
            }
        }
    }
    __builtin_amdgcn_wave_barrier();

    // ---- GEMM3: out[64][96] = F @ Wm1T (K=192) + bm1 + hp -> hout ----
    {
        f32x4 acc3[6];
        #pragma unroll
        for (int i = 0; i < 6; i++) acc3[i] = (f32x4){0.f, 0.f, 0.f, 0.f};
        #pragma unroll
        for (int kc = 0; kc < 192; kc += 32) {
            s16x8 a = *(s16x8*)&sU[(16 * w + fr) * 200 + kc + kg * 8];
            #pragma unroll
            for (int nt = 0; nt < 6; nt++) {
                s16x8 b = *(const s16x8*)(Wm1T16 + (16 * nt + fr) * 192 + kc + kg * 8);
                acc3[nt] = __builtin_amdgcn_mfma_f32_16x16x32_bf16(a, b, acc3[nt], 0, 0, 0);
            }
        }
        #pragma unroll
        for (int nt = 0; nt < 6; nt++) {
            int col = nt * 16 + fr;
            float bv = bm1[col];
            #pragma unroll
            for (int r = 0; r < 4; r++) {
                int row = 16 * w + 4 * kg + r;
                int grow = m0 + row;
                if (grow < M)
                    hout[(size_t)grow * 96 + col] =
                        acc3[nt][r] + bv + b2f(sHP[row * 104 + col]);
            }
        }
    }
}

// ---------------------------------------------------------------------------
extern "C" void kernel_launch(void* const* d_in, const int* in_sizes, int n_in,
                              void* d_out, int out_size, void* d_ws, size_t ws_size,
                              hipStream_t stream)
{
    (void)n_in; (void)out_size; (void)ws_size;
    const float* feat = (const float*)d_in[0];
    const float* edge = (const float*)d_in[1];
    const float* Wq   = (const float*)d_in[2];
    const float* bq   = (const float*)d_in[3];
    const float* Wk   = (const float*)d_in[4];
    const float* bk   = (const float*)d_in[5];
    const float* Wv   = (const float*)d_in[6];
    const float* bv   = (const float*)d_in[7];
    const float* We   = (const float*)d_in[8];
    const float* be   = (const float*)d_in[9];
    const float* Wb   = (const float*)d_in[10];
    const float* bb   = (const float*)d_in[11];
    const float* Wvv  = (const float*)d_in[12];
    const float* bvv  = (const float*)d_in[13];
    const float* Wf0  = (const float*)d_in[14];
    const float* bf0  = (const float*)d_in[15];
    const float* Wf1  = (const float*)d_in[16];
    const float* bf1  = (const float*)d_in[17];
    const float* Wm0  = (const float*)d_in[18];
    const float* bm0  = (const float*)d_in[19];
    const float* Wm1  = (const float*)d_in[20];
    const float* bm1  = (const float*)d_in[21];
    const float* g_n0 = (const float*)d_in[22];
    const float* b_n0 = (const float*)d_in[23];
    const float* g_e0 = (const float*)d_in[24];
    const float* b_e0 = (const float*)d_in[25];
    const float* g_e1 = (const float*)d_in[26];
    const float* b_e1 = (const float*)d_in[27];
    const float* g_m  = (const float*)d_in[28];
    const float* b_m  = (const float*)d_in[29];
    const float* wsc  = (const float*)d_in[30];
    const int*   src  = (const int*)d_in[31];
    const int*   dst  = (const int*)d_in[32];

    const int N = in_sizes[0] / 96;
    const int E = in_sizes[1] / 32;

    unsigned short* agg16 = (unsigned short*)d_ws;          // N*128 bf16
    unsigned short* qkv16 = agg16 + (size_t)N * 128;        // N*288 bf16
    unsigned short* exve16 = qkv16 + (size_t)N * 288;       // E*64 bf16
    unsigned short* wbwe16 = exve16 + (size_t)E * 64;       // 2048
    unsigned short* wf0t16 = wbwe16 + 2048;                 // 2048
    unsigned short* wf1t16 = wf0t16 + 2048;                 // 2048
    unsigned short* wvvt16 = wf1t16 + 2048;                 // 12288
    unsigned short* wm0t16 = wvvt16 + 12288;                // 18432
    unsigned short* wm1t16 = wm0t16 + 18432;                // 18432
    int4*  slotinfo = (int4*)(((uintptr_t)(wm1t16 + 18432) + 15) & ~(uintptr_t)15);
    int*   rank  = (int*)(slotinfo + E);                    // E
    int*   cnt   = rank + E;                                // N
    int*   offv  = cnt + N;                                 // N
    float* hout  = (float*)d_out;
    float* eoutp = (float*)d_out + (size_t)N * 96;

    hipMemsetAsync(cnt, 0, (size_t)N * sizeof(int), stream);

    const int mt = (N + 63) / 64;
    const int et = (E + 255) / 256;

    // weight prep (once) + CSR bucketing
    prep_kernel<<<1, 256, 0, stream>>>(Wb, We, Wf0, Wf1, Wvv, Wm0, Wm1,
                                       wbwe16, wf0t16, wf1t16, wvvt16, wm0t16, wm1t16);
    count_kernel<<<et, 256, 0, stream>>>(dst, cnt, rank, E);
    scan_kernel<<<1, 1024, 0, stream>>>(cnt, offv, N);
    scatter_kernel<<<et, 256, 0, stream>>>(dst, src, offv, rank, slotinfo, E);

    // qkv16 = bf16( LN(feat) @ [Wq|Wk|Wv] )
    mgemm_kernel<1,1,0,0,0><<<dim3(mt, 3), 256, 0, stream>>>(
        feat, 96, Wq, Wk, Wv, 96, bq, bk, bv, g_n0, b_n0,
        nullptr, nullptr, nullptr, 0, qkv16, N, 96);

    // fused edge tile pass
    edge_tile_kernel<<<(E + 63) / 64, 256, 0, stream>>>(edge, qkv16, slotinfo,
                                             wbwe16, wf0t16, wf1t16,
                                             be, bb, bf0, bf1,
                                             g_e0, b_e0, g_e1, b_e1,
                                             exve16, eoutp, E);

    // gather per node -> normalized agg16[N,128]
    gather_kernel<<<(N + 3) / 4, 256, 0, stream>>>(exve16, qkv16, slotinfo, offv, cnt, agg16, N);

    // fused node MLP: h_out = hp + relu(LN(hp)@Wm0)@Wm1,  hp = feat*(1+w)+agg@Wvv
    mlp_kernel<<<mt, 256, 0, stream>>>(agg16, feat, wvvt16, wm0t16, wm1t16,
                                       bvv, bm0, bm1, g_m, b_m, wsc, hout, N);
}

// Round 21
// 782.226 us; speedup vs baseline: 1.0507x; 1.0507x over previous
//
#include <hip/hip_runtime.h>
#include <cstdint>
#include <cstddef>

// ---------------------------------------------------------------------------
// EGT layer.  N nodes (DIM=96, H=32, HD=3), E edges.
// Round-18 structure (best known: 783.9us) + 4-deep gather pipeline.
// CSR slotinfo[slot]={eidx,src,dst,0}; qkv bf16-only; edge weights prepped
// bf16 [N][K]; edge_tile 64 CSR slots/block, global-L1 weights, 29.7KB LDS.
// ---------------------------------------------------------------------------

typedef short  s16x8 __attribute__((ext_vector_type(8)));
typedef short  s16x4 __attribute__((ext_vector_type(4)));
typedef float  f32x4 __attribute__((ext_vector_type(4)));

__device__ __forceinline__ unsigned short f2b(float x) {
    union { float f; unsigned u; } v; v.f = x;
    unsigned r = v.u + 0x7FFF + ((v.u >> 16) & 1);   // RNE
    return (unsigned short)(r >> 16);
}
__device__ __forceinline__ float b2f(unsigned short u) {
    union { unsigned u; float f; } v; v.u = ((unsigned)u) << 16; return v.f;
}

// ---------------- MFMA node GEMM ----------------
template<int MULTI, int LNA, int A16, int RELU, int RES>
__global__ __launch_bounds__(256) void mgemm_kernel(
    const void* __restrict__ Av, int lda,
    const float* __restrict__ B0, const float* __restrict__ B1,
    const float* __restrict__ B2, int ldb,
    const float* __restrict__ bias0, const float* __restrict__ bias1,
    const float* __restrict__ bias2,
    const float* __restrict__ lng, const float* __restrict__ lnbv,
    const float* __restrict__ resid, const float* __restrict__ wptr,
    float* __restrict__ C, int ldc, unsigned short* __restrict__ C16,
    int M, int K)
{
    __shared__ unsigned short sAL[64 * 200];
    __shared__ unsigned short sB[96 * 40];

    const int tid = threadIdx.x;
    const int m0 = blockIdx.x * 64;
    const int y  = blockIdx.y;
    const float* B = MULTI ? (y == 0 ? B0 : (y == 1 ? B1 : B2)) : B0;
    const int nbB = MULTI ? 0 : y * 96;
    const int nbC = y * 96;
    const int w = tid >> 6, l = tid & 63, fr = l & 15, kg = l >> 4;
    const int KP = K + 8;

    if (LNA) {
        const float* Af = (const float*)Av;
        const int row = 16 * w + fr;
        const int grow = m0 + row;
        float x[24];
        if (grow < M) {
            #pragma unroll
            for (int t = 0; t < 6; t++)
                *(float4*)&x[t * 4] = *(const float4*)(Af + (size_t)grow * lda + 24 * kg + t * 4);
        } else {
            #pragma unroll
            for (int t = 0; t < 24; t++) x[t] = 0.f;
        }
        float s = 0.f;
        #pragma unroll
        for (int t = 0; t < 24; t++) s += x[t];
        s += __shfl_xor(s, 16, 64); s += __shfl_xor(s, 32, 64);
        float mu = s * (1.f / 96.f);
        float v2 = 0.f;
        #pragma unroll
        for (int t = 0; t < 24; t++) { float d = x[t] - mu; v2 += d * d; }
        v2 += __shfl_xor(v2, 16, 64); v2 += __shfl_xor(v2, 32, 64);
        float rs = rsqrtf(v2 * (1.f / 96.f) + 1e-5f);
        #pragma unroll
        for (int t3 = 0; t3 < 3; t3++) {
            s16x8 yv;
            #pragma unroll
            for (int u = 0; u < 8; u++) {
                int cidx = 24 * kg + t3 * 8 + u;
                yv[u] = (short)f2b((x[t3 * 8 + u] - mu) * rs * lng[cidx] + lnbv[cidx]);
            }
            *(s16x8*)&sAL[row * KP + 24 * kg + t3 * 8] = yv;
        }
    } else {
        const int nseg = K >> 3;
        for (int idx = tid; idx < 64 * nseg; idx += 256) {
            int row = idx / nseg, k8 = (idx - row * nseg) * 8;
            int grow = m0 + row;
            s16x8 a8 = (s16x8){0, 0, 0, 0, 0, 0, 0, 0};
            if (grow < M) {
                if (A16) {
                    a8 = *(const s16x8*)((const unsigned short*)Av + (size_t)grow * lda + k8);
                } else {
                    const float* Af = (const float*)Av;
                    float4 v0 = *(const float4*)(Af + (size_t)grow * lda + k8);
                    float4 v1 = *(const float4*)(Af + (size_t)grow * lda + k8 + 4);
                    a8[0] = (short)f2b(v0.x); a8[1] = (short)f2b(v0.y);
                    a8[2] = (short)f2b(v0.z); a8[3] = (short)f2b(v0.w);
                    a8[4] = (short)f2b(v1.x); a8[5] = (short)f2b(v1.y);
                    a8[6] = (short)f2b(v1.z); a8[7] = (short)f2b(v1.w);
                }
            }
            *(s16x8*)&sAL[row * KP + k8] = a8;
        }
    }

    f32x4 acc[6];
    #pragma unroll
    for (int i = 0; i < 6; i++) acc[i] = (f32x4){0.f, 0.f, 0.f, 0.f};

    for (int kc = 0; kc < K; kc += 32) {
        #pragma unroll
        for (int r = 0; r < 3; r++) {
            int idx = tid + 256 * r;
            int k = idx / 24, n4 = (idx - k * 24) * 4;
            float4 v = *(const float4*)(B + (size_t)(kc + k) * ldb + nbB + n4);
            sB[(n4 + 0) * 40 + k] = f2b(v.x);
            sB[(n4 + 1) * 40 + k] = f2b(v.y);
            sB[(n4 + 2) * 40 + k] = f2b(v.z);
            sB[(n4 + 3) * 40 + k] = f2b(v.w);
        }
        __syncthreads();
        {
            s16x8 a = *(s16x8*)&sAL[(16 * w + fr) * KP + kc + kg * 8];
            #pragma unroll
            for (int nt = 0; nt < 6; nt++) {
                s16x8 b = *(s16x8*)&sB[(16 * nt + fr) * 40 + kg * 8];
                acc[nt] = __builtin_amdgcn_mfma_f32_16x16x32_bf16(a, b, acc[nt], 0, 0, 0);
            }
        }
        __syncthreads();
    }

    float scale = 1.f;
    if (RES) scale = wptr ? (1.f + wptr[0]) : 1.f;
    const float* biasp = MULTI ? (y == 0 ? bias0 : (y == 1 ? bias1 : bias2)) : bias0;
    const int bbase = MULTI ? 0 : nbB;

    #pragma unroll
    for (int nt = 0; nt < 6; nt++) {
        int cl = nt * 16 + fr;
        float bv = biasp[bbase + cl];
        int gcol = nbC + cl;
        #pragma unroll
        for (int r = 0; r < 4; r++) {
            int row = m0 + 16 * w + 4 * kg + r;
            if (row >= M) continue;
            float v = acc[nt][r] + bv;
            if (RELU) v = fmaxf(v, 0.f);
            if (MULTI) {
                C16[(size_t)row * 288 + gcol] = f2b(v);
            } else {
                if (RES) v += scale * resid[(size_t)row * ldc + gcol];
                C[(size_t)row * ldc + gcol] = v;
            }
        }
    }
}

// ---------------- prep: edge weights -> bf16 [N][K] layouts (once) ---------
__global__ __launch_bounds__(256) void prep_kernel(
    const float* __restrict__ Wb, const float* __restrict__ We,
    const float* __restrict__ Wf0, const float* __restrict__ Wf1,
    unsigned short* __restrict__ WbWe16, unsigned short* __restrict__ Wf0T16,
    unsigned short* __restrict__ Wf1T16)
{
    const int t = threadIdx.x;
    for (int i = t; i < 2048; i += 256) {
        int n = i >> 5, k = i & 31;
        float v = (n < 32) ? Wb[k * 32 + n] : We[k * 32 + (n - 32)];
        WbWe16[i] = f2b(v);
    }
    for (int i = t; i < 2048; i += 256) {
        int n = i >> 5, k = i & 31;
        Wf0T16[i] = f2b(Wf0[k * 64 + n]);
    }
    for (int i = t; i < 2048; i += 256) {
        int n = i >> 6, k = i & 63;
        Wf1T16[i] = f2b(Wf1[k * 32 + n]);
    }
}

// ---------------- CSR bucketing ----------------
__global__ __launch_bounds__(256) void count_kernel(
    const int* __restrict__ dst, int* __restrict__ cnt,
    int* __restrict__ rank, int E)
{
    int i = blockIdx.x * 256 + threadIdx.x;
    if (i < E) rank[i] = atomicAdd(&cnt[dst[i]], 1);
}

__global__ __launch_bounds__(1024) void scan_kernel(
    const int* __restrict__ cnt, int* __restrict__ off, int N)
{
    __shared__ int s[1024];
    const int tid = threadIdx.x;
    const int chunk = (N + 1023) >> 10;
    const int lo = tid * chunk;
    const int hi = min(lo + chunk, N);
    int sum = 0;
    for (int i = lo; i < hi; i++) sum += cnt[i];
    s[tid] = sum;
    __syncthreads();
    for (int d = 1; d < 1024; d <<= 1) {
        int v = (tid >= d) ? s[tid - d] : 0;
        __syncthreads();
        s[tid] += v;
        __syncthreads();
    }
    int base = (tid == 0) ? 0 : s[tid - 1];
    for (int i = lo; i < hi; i++) {
        off[i] = base;
        base += cnt[i];
    }
}

__global__ __launch_bounds__(256) void scatter_kernel(
    const int* __restrict__ dst, const int* __restrict__ src,
    const int* __restrict__ off, const int* __restrict__ rank,
    int4* __restrict__ slotinfo, int E)
{
    int i = blockIdx.x * 256 + threadIdx.x;
    if (i < E) {
        int d = dst[i];
        int p = off[d] + rank[i];
        slotinfo[p] = make_int4(i, src[i], d, 0);
    }
}

// ---------------- edge tile kernel: 64 CSR slots per block ------------------
__global__ __launch_bounds__(256, 5) void edge_tile_kernel(
    const float* __restrict__ edge, const unsigned short* __restrict__ qkv16,
    const int4* __restrict__ slotinfo,
    const unsigned short* __restrict__ WbWe16,
    const unsigned short* __restrict__ Wf0T16,
    const unsigned short* __restrict__ Wf1T16,
    const float* __restrict__ be, const float* __restrict__ bb,
    const float* __restrict__ bf0, const float* __restrict__ bf1,
    const float* __restrict__ ge0, const float* __restrict__ be0,
    const float* __restrict__ ge1, const float* __restrict__ be1,
    unsigned short* __restrict__ exve16, float* __restrict__ eout, int E)
{
    __shared__ float          sEV[64 * 36];
    __shared__ unsigned short sQK[64 * 44];
    __shared__ unsigned short sA [64 * 40];
    __shared__ unsigned short sX [64 * 76];

    const int tid = threadIdx.x;
    const long long e0 = (long long)blockIdx.x * 64;
    const int w  = tid >> 6;
    const int l  = tid & 63;
    const int fr = l & 15;
    const int kg = l >> 4;

    {
        const int row = tid >> 2;
        const int j   = tid & 3;
        long long s = e0 + row;
        float qv[24], kv[24];
        if (s < E) {
            int4 si = slotinfo[s];
            const unsigned short* qp = qkv16 + (size_t)si.z * 288 + 24 * j;
            const unsigned short* kp = qkv16 + (size_t)si.y * 288 + 96 + 24 * j;
            #pragma unroll
            for (int t = 0; t < 3; t++) {
                s16x8 qa = *(const s16x8*)(qp + 8 * t);
                s16x8 ka = *(const s16x8*)(kp + 8 * t);
                #pragma unroll
                for (int u = 0; u < 8; u++) {
                    qv[8 * t + u] = b2f((unsigned short)qa[u]);
                    kv[8 * t + u] = b2f((unsigned short)ka[u]);
                }
            }
        } else {
            #pragma unroll
            for (int t = 0; t < 24; t++) { qv[t] = 0.f; kv[t] = 0.f; }
        }
        s16x8 qkb;
        #pragma unroll
        for (int t = 0; t < 8; t++) {
            float d = kv[3*t]*qv[3*t] + kv[3*t+1]*qv[3*t+1] + kv[3*t+2]*qv[3*t+2];
            qkb[t] = (short)f2b(0.5f * d);
        }
        *(s16x8*)&sQK[row * 44 + 8 * j] = qkb;
    }
    #pragma unroll
    for (int rr = 0; rr < 2; rr++) {
        int idx = tid + 256 * rr;
        int row = idx >> 3, c4 = (idx & 7) * 4;
        long long s = e0 + row;
        float4 v = make_float4(0.f, 0.f, 0.f, 0.f);
        if (s < E) {
            int ge = slotinfo[s].x;
            v = *(const float4*)(edge + (size_t)ge * 32 + c4);
        }
        *(float4*)&sEV[row * 36 + c4] = v;
    }
    __syncthreads();

    {
        const int row = 16 * w + (tid & 15);
        const int q = (tid & 63) >> 4;
        float x[8];
        *(float4*)&x[0] = *(float4*)&sEV[row * 36 + 8 * q];
        *(float4*)&x[4] = *(float4*)&sEV[row * 36 + 8 * q + 4];
        float s = x[0] + x[1] + x[2] + x[3] + x[4] + x[5] + x[6] + x[7];
        s += __shfl_xor(s, 16, 64); s += __shfl_xor(s, 32, 64);
        float mu = s * (1.f / 32.f);
        float v2 = 0.f;
        #pragma unroll
        for (int i = 0; i < 8; i++) { float d = x[i] - mu; v2 += d * d; }
        v2 += __shfl_xor(v2, 16, 64); v2 += __shfl_xor(v2, 32, 64);
        float rs = rsqrtf(v2 * (1.f / 32.f) + 1e-5f);
        float4 g1 = *(const float4*)(ge0 + 8 * q), g2 = *(const float4*)(ge0 + 8 * q + 4);
        float4 b1 = *(const float4*)(be0 + 8 * q), b2 = *(const float4*)(be0 + 8 * q + 4);
        float gg[8] = {g1.x, g1.y, g1.z, g1.w, g2.x, g2.y, g2.z, g2.w};
        float bs[8] = {b1.x, b1.y, b1.z, b1.w, b2.x, b2.y, b2.z, b2.w};
        s16x8 y;
        #pragma unroll
        for (int i = 0; i < 8; i++)
            y[i] = (short)f2b((x[i] - mu) * rs * gg[i] + bs[i]);
        *(s16x8*)&sA[row * 40 + 8 * q] = y;
    }
    __builtin_amdgcn_wave_barrier();

    f32x4 acc[4];
    {
        s16x8 a = *(s16x8*)&sA[(16 * w + fr) * 40 + kg * 8];
        #pragma unroll
        for (int nt = 0; nt < 4; nt++) {
            s16x8 b = *(const s16x8*)(WbWe16 + (16 * nt + fr) * 32 + kg * 8);
            f32x4 z = {0.f, 0.f, 0.f, 0.f};
            acc[nt] = __builtin_amdgcn_mfma_f32_16x16x32_bf16(a, b, z, 0, 0, 0);
        }
    }

    #pragma unroll
    for (int nt = 0; nt < 2; nt++) {
        int col = nt * 16 + fr;
        float bbv = bb[col];
        #pragma unroll
        for (int r = 0; r < 4; r++) {
            int row = 16 * w + 4 * kg + r;
            float sc = acc[nt][r] + b2f(sQK[row * 44 + col]) + bbv;
            sX[row * 76 + col] = f2b(__expf(sc));
            float er = sc + sEV[row * 36 + col];
            sEV[row * 36 + col] = er;
        }
    }
    #pragma unroll
    for (int nt = 2; nt < 4; nt++) {
        int col = (nt - 2) * 16 + fr;
        float bev = be[col];
        #pragma unroll
        for (int r = 0; r < 4; r++) {
            int row = 16 * w + 4 * kg + r;
            sX[row * 76 + 32 + col] = f2b(acc[nt][r] + bev);
        }
    }
    __syncthreads();

    #pragma unroll
    for (int rr = 0; rr < 2; rr++) {
        int idx = tid + 256 * rr;
        int row = idx >> 3, c8 = (idx & 7) * 8;
        long long s = e0 + row;
        if (s < E)
            *(s16x8*)(exve16 + (size_t)s * 64 + c8) = *(s16x8*)&sX[row * 76 + c8];
    }
    {
        const int row = 16 * w + (tid & 15);
        const int q = (tid & 63) >> 4;
        float x[8];
        *(float4*)&x[0] = *(float4*)&sEV[row * 36 + 8 * q];
        *(float4*)&x[4] = *(float4*)&sEV[row * 36 + 8 * q + 4];
        float s = x[0] + x[1] + x[2] + x[3] + x[4] + x[5] + x[6] + x[7];
        s += __shfl_xor(s, 16, 64); s += __shfl_xor(s, 32, 64);
        float mu = s * (1.f / 32.f);
        float v2 = 0.f;
        #pragma unroll
        for (int i = 0; i < 8; i++) { float d = x[i] - mu; v2 += d * d; }
        v2 += __shfl_xor(v2, 16, 64); v2 += __shfl_xor(v2, 32, 64);
        float rs = rsqrtf(v2 * (1.f / 32.f) + 1e-5f);
        float4 g1 = *(const float4*)(ge1 + 8 * q), g2 = *(const float4*)(ge1 + 8 * q + 4);
        float4 b1 = *(const float4*)(be1 + 8 * q), b2 = *(const float4*)(be1 + 8 * q + 4);
        float gg[8] = {g1.x, g1.y, g1.z, g1.w, g2.x, g2.y, g2.z, g2.w};
        float bs[8] = {b1.x, b1.y, b1.z, b1.w, b2.x, b2.y, b2.z, b2.w};
        s16x8 y;
        #pragma unroll
        for (int i = 0; i < 8; i++)
            y[i] = (short)f2b((x[i] - mu) * rs * gg[i] + bs[i]);
        *(s16x8*)&sA[row * 40 + 8 * q] = y;
    }
    __syncthreads();

    {
        s16x8 a = *(s16x8*)&sA[(16 * w + fr) * 40 + kg * 8];
        #pragma unroll
        for (int nt = 0; nt < 4; nt++) {
            s16x8 b = *(const s16x8*)(Wf0T16 + (16 * nt + fr) * 32 + kg * 8);
            f32x4 z = {0.f, 0.f, 0.f, 0.f};
            f32x4 a2 = __builtin_amdgcn_mfma_f32_16x16x32_bf16(a, b, z, 0, 0, 0);
            int col = nt * 16 + fr;
            float b0v = bf0[col];
            #pragma unroll
            for (int r = 0; r < 4; r++) {
                int row = 16 * w + 4 * kg + r;
                sX[row * 76 + col] = f2b(fmaxf(a2[r] + b0v, 0.f));
            }
        }
    }
    __builtin_amdgcn_wave_barrier();

    {
        s16x8 a0 = *(s16x8*)&sX[(16 * w + fr) * 76 + kg * 8];
        s16x8 a1 = *(s16x8*)&sX[(16 * w + fr) * 76 + 32 + kg * 8];
        #pragma unroll
        for (int nt = 0; nt < 2; nt++) {
            s16x8 b0 = *(const s16x8*)(Wf1T16 + (16 * nt + fr) * 64 + kg * 8);
            s16x8 b1 = *(const s16x8*)(Wf1T16 + (16 * nt + fr) * 64 + 32 + kg * 8);
            f32x4 z = {0.f, 0.f, 0.f, 0.f};
            f32x4 t = __builtin_amdgcn_mfma_f32_16x16x32_bf16(a0, b0, z, 0, 0, 0);
            t = __builtin_amdgcn_mfma_f32_16x16x32_bf16(a1, b1, t, 0, 0, 0);
            int col = nt * 16 + fr;
            float bf1v = bf1[col];
            #pragma unroll
            for (int r = 0; r < 4; r++) {
                int row = 16 * w + 4 * kg + r;
                float out = t[r] + sEV[row * 36 + col] + bf1v;
                sEV[row * 36 + col] = out;
            }
        }
    }
    __syncthreads();

    #pragma unroll
    for (int rr = 0; rr < 2; rr++) {
        int idx = tid + 256 * rr;
        int row = idx >> 3, c4 = (idx & 7) * 4;
        long long s = e0 + row;
        if (s < E) {
            int ge = slotinfo[s].x;
            *(float4*)(eout + (size_t)ge * 32 + c4) = *(float4*)&sEV[row * 36 + c4];
        }
    }
}

// ---------------- gather: wave/node, 4 edges in flight per half ------------
__global__ __launch_bounds__(256) void gather_kernel(
    const unsigned short* __restrict__ exve16, const unsigned short* __restrict__ qkv16,
    const int4* __restrict__ slotinfo, const int* __restrict__ off,
    const int* __restrict__ cnt, unsigned short* __restrict__ agg16, int N)
{
    __shared__ unsigned short sV16[4][2][4][96];
    __shared__ unsigned short sE16[4][2][4][64];
    const int wave = threadIdx.x >> 6;
    const int lane = threadIdx.x & 63;
    const int head = lane & 31;
    const int half = lane >> 5;
    int n = blockIdx.x * 4 + wave;
    if (n >= N) return;
    const int o = off[n], d = cnt[n];
    float a0 = 0.f, a1 = 0.f, a2 = 0.f, a3 = 0.f, den = 0.f;
    for (int i = half; i < d; i += 8) {
        #pragma unroll
        for (int b = 0; b < 4; b++) {
            int ii = i + 2 * b;
            if (ii < d) {
                int sn = slotinfo[o + ii].y;
                const unsigned short* vr = qkv16 + (size_t)sn * 288 + 192;
                const unsigned short* er = exve16 + (size_t)(o + ii) * 64;
                if (head < 12)
                    *(s16x8*)&sV16[wave][half][b][head * 8] = *(const s16x8*)(vr + head * 8);
                else if (head >= 24)
                    *(s16x8*)&sE16[wave][half][b][(head - 24) * 8] = *(const s16x8*)(er + (head - 24) * 8);
            }
        }
        __builtin_amdgcn_wave_barrier();
        #pragma unroll
        for (int b = 0; b < 4; b++) {
            int ii = i + 2 * b;
            if (ii < d) {
                float ex = b2f(sE16[wave][half][b][head]);
                float vv = b2f(sE16[wave][half][b][32 + head]);
                a0 += ex * b2f(sV16[wave][half][b][head * 3]);
                a1 += ex * b2f(sV16[wave][half][b][head * 3 + 1]);
                a2 += ex * b2f(sV16[wave][half][b][head * 3 + 2]);
                a3 += ex * vv;
                den += ex;
            }
        }
        __builtin_amdgcn_wave_barrier();
    }
    a0 += __shfl_xor(a0, 32, 64);
    a1 += __shfl_xor(a1, 32, 64);
    a2 += __shfl_xor(a2, 32, 64);
    a3 += __shfl_xor(a3, 32, 64);
    den += __shfl_xor(den, 32, 64);
    if (half == 0) {
        float sc = (d > 0) ? 1.f / den : 0.f;
        s16x4 ov;
        ov[0] = (short)f2b(a0 * sc);
        ov[1] = (short)f2b(a1 * sc);
        ov[2] = (short)f2b(a2 * sc);
        ov[3] = (short)f2b(a3 * sc);
        *(s16x4*)(agg16 + (size_t)n * 128 + head * 4) = ov;
    }
}

// ---------------------------------------------------------------------------
extern "C" void kernel_launch(void* const* d_in, const int* in_sizes, int n_in,
                              void* d_out, int out_size, void* d_ws, size_t ws_size,
                              hipStream_t stream)
{
    (void)n_in; (void)out_size; (void)ws_size;
    const float* feat = (const float*)d_in[0];
    const float* edge = (const float*)d_in[1];
    const float* Wq   = (const float*)d_in[2];
    const float* bq   = (const float*)d_in[3];
    const float* Wk   = (const float*)d_in[4];
    const float* bk   = (const float*)d_in[5];
    const float* Wv   = (const float*)d_in[6];
    const float* bv   = (const float*)d_in[7];
    const float* We   = (const float*)d_in[8];
    const float* be   = (const float*)d_in[9];
    const float* Wb   = (const float*)d_in[10];
    const float* bb   = (const float*)d_in[11];
    const float* Wvv  = (const float*)d_in[12];
    const float* bvv  = (const float*)d_in[13];
    const float* Wf0  = (const float*)d_in[14];
    const float* bf0  = (const float*)d_in[15];
    const float* Wf1  = (const float*)d_in[16];
    const float* bf1  = (const float*)d_in[17];
    const float* Wm0  = (const float*)d_in[18];
    const float* bm0  = (const float*)d_in[19];
    const float* Wm1  = (const float*)d_in[20];
    const float* bm1  = (const float*)d_in[21];
    const float* g_n0 = (const float*)d_in[22];
    const float* b_n0 = (const float*)d_in[23];
    const float* g_e0 = (const float*)d_in[24];
    const float* b_e0 = (const float*)d_in[25];
    const float* g_e1 = (const float*)d_in[26];
    const float* b_e1 = (const float*)d_in[27];
    const float* g_m  = (const float*)d_in[28];
    const float* b_m  = (const float*)d_in[29];
    const float* wsc  = (const float*)d_in[30];
    const int*   src  = (const int*)d_in[31];
    const int*   dst  = (const int*)d_in[32];

    const int N = in_sizes[0] / 96;
    const int E = in_sizes[1] / 32;

    float* ws    = (float*)d_ws;
    float* hp    = ws;                                      // N*96 f32
    float* tbuf  = hp + (size_t)N * 96;                     // N*192 f32
    unsigned short* agg16 = (unsigned short*)(tbuf + (size_t)N * 192); // N*128 bf16
    unsigned short* qkv16 = agg16 + (size_t)N * 128;        // N*288 bf16
    unsigned short* exve16 = qkv16 + (size_t)N * 288;       // E*64 bf16
    unsigned short* wbwe16 = exve16 + (size_t)E * 64;       // 2048
    unsigned short* wf0t16 = wbwe16 + 2048;                 // 2048
    unsigned short* wf1t16 = wf0t16 + 2048;                 // 2048
    int4*  slotinfo = (int4*)(((uintptr_t)(wf1t16 + 2048) + 15) & ~(uintptr_t)15);
    int*   rank  = (int*)(slotinfo + E);                    // E
    int*   cnt   = rank + E;                                // N
    int*   offv  = cnt + N;                                 // N
    float* hout  = (float*)d_out;
    float* eoutp = (float*)d_out + (size_t)N * 96;

    hipMemsetAsync(cnt, 0, (size_t)N * sizeof(int), stream);

    const int mt = (N + 63) / 64;
    const int et = (E + 255) / 256;

    // weight prep (once) + CSR bucketing
    prep_kernel<<<1, 256, 0, stream>>>(Wb, We, Wf0, Wf1, wbwe16, wf0t16, wf1t16);
    count_kernel<<<et, 256, 0, stream>>>(dst, cnt, rank, E);
    scan_kernel<<<1, 1024, 0, stream>>>(cnt, offv, N);
    scatter_kernel<<<et, 256, 0, stream>>>(dst, src, offv, rank, slotinfo, E);

    // qkv16 = bf16( LN(feat) @ [Wq|Wk|Wv] )
    mgemm_kernel<1,1,0,0,0><<<dim3(mt, 3), 256, 0, stream>>>(
        feat, 96, Wq, Wk, Wv, 96, bq, bk, bv, g_n0, b_n0,
        nullptr, nullptr, nullptr, 0, qkv16, N, 96);

    // fused edge tile pass
    edge_tile_kernel<<<(E + 63) / 64, 256, 0, stream>>>(edge, qkv16, slotinfo,
                                             wbwe16, wf0t16, wf1t16,
                                             be, bb, bf0, bf1,
                                             g_e0, b_e0, g_e1, b_e1,
                                             exve16, eoutp, E);

    // gather per node -> normalized agg16[N,128]
    gather_kernel<<<(N + 3) / 4, 256, 0, stream>>>(exve16, qkv16, slotinfo, offv, cnt, agg16, N);

    // h_pre = feat*(1+w) + agg @ Wvv + bvv   (bf16 A)
    mgemm_kernel<0,0,1,0,1><<<dim3(mt, 1), 256, 0, stream>>>(
        agg16, 128, Wvv, Wvv, Wvv, 96, bvv, bvv, bvv, nullptr, nullptr,
        feat, wsc, hp, 96, nullptr, N, 128);
    // t = relu(LN(hp) @ Wm0 + bm0)   (LN fused)
    mgemm_kernel<0,1,0,1,0><<<dim3(mt, 2), 256, 0, stream>>>(
        hp, 96, Wm0, Wm0, Wm0, 192, bm0, bm0, bm0, g_m, b_m,
        nullptr, nullptr, tbuf, 192, nullptr, N, 96);
    // h_out = hp + t @ Wm1 + bm1
    mgemm_kernel<0,0,0,0,1><<<dim3(mt, 1), 256, 0, stream>>>(
        tbuf, 192, Wm1, Wm1, Wm1, 96, bm1, bm1, bm1, nullptr, nullptr,
        hp, nullptr, hout, 96, nullptr, N, 192);
}